// Round 2
// baseline (470.602 us; speedup 1.0000x reference)
//
#include <hip/hip_runtime.h>
#include <hip/hip_bf16.h>
#include <math.h>

#define N_TOTAL 32768
#define E_TOTAL 524288
#define NUM_GRAPHS 64
#define NPG 512
#define EMB 128
#define MAXD 64
#define KTOP 64
#define LATENT 513

// ---------------- setup kernels ----------------

__global__ __launch_bounds__(256) void k_init(int* __restrict__ deg, int* __restrict__ cnt) {
    int i = blockIdx.x * 256 + threadIdx.x;
    if (i < N_TOTAL) { deg[i] = 1; cnt[i] = 0; }   // deg starts at 1 (self loop in src concat)
}

__global__ __launch_bounds__(256) void k_build(const int* __restrict__ ei,
                                               int* __restrict__ deg, int* __restrict__ cnt,
                                               int* __restrict__ adj) {
    int e = blockIdx.x * 256 + threadIdx.x;
    if (e >= E_TOTAL) return;
    int s = ei[e];
    int d = ei[E_TOTAL + e];
    atomicAdd(&deg[s], 1);
    int slot = atomicAdd(&cnt[d], 1);
    if (slot < MAXD) adj[(size_t)d * MAXD + slot] = s;
}

__global__ __launch_bounds__(256) void k_embed(const int* __restrict__ x,
                                               const float* __restrict__ emb,
                                               float* __restrict__ H0) {
    int t = blockIdx.x * 256 + threadIdx.x;       // 32768*32 float4 slots
    int node = t >> 5, q = t & 31;
    ((float4*)H0)[(size_t)node * 32 + q] = ((const float4*)emb)[(size_t)x[node] * 32 + q];
}

// ---------------- aggregation: Agg[v] = H[v] + sum_{u in in(v)} H[u] ----------------

__global__ __launch_bounds__(256) void k_agg(const float* __restrict__ Hin,
                                             float* __restrict__ Agg,
                                             const int* __restrict__ adj,
                                             const int* __restrict__ cnt) {
    int bid = blockIdx.x;                 // 8192 blocks
    int xcd = bid & 7;
    int j = bid >> 3;                     // 0..1023
    int g = (xcd << 3) + (j >> 7);        // 8 graphs per XCD -> per-XCD L2 residency
    int chunk = j & 127;
    int wv = threadIdx.x >> 6, lane = threadIdx.x & 63;
    int v = g * NPG + chunk * 4 + wv;

    int c = cnt[v]; if (c > MAXD) c = MAXD;
    const float2* hin = (const float2*)Hin;
    float2 s = hin[(size_t)v * 64 + lane];          // self loop
    const int* av = adj + (size_t)v * MAXD;
    for (int i = 0; i < c; ++i) {
        int u = av[i];
        float2 t = hin[(size_t)u * 64 + lane];
        s.x += t.x; s.y += t.y;
    }
    ((float2*)Agg)[(size_t)v * 64 + lane] = s;
}

// ---------------- GEMM + bias + 1/deg + tanh:  Hout = tanh((Agg@W + (cnt+1)b)/deg) ---------

__global__ __launch_bounds__(256) void k_gemm_tanh(const float* __restrict__ Agg,
                                                   const float* __restrict__ W,
                                                   const float* __restrict__ bvec,
                                                   float* __restrict__ Hout,
                                                   const int* __restrict__ cnt,
                                                   const int* __restrict__ deg) {
    __shared__ float As[128][68];   // 128 rows x 64 k-half, pad to 68 (16B-aligned rows)
    __shared__ float Ws[64][64];    // 64 k x 64 cols
    int tid = threadIdx.x;
    int bid = blockIdx.x;
    int rb = bid >> 1, cbk = bid & 1;
    int tc = tid & 7;               // 8 col groups of 8 cols
    int tr = tid >> 3;              // 32 row groups of 4 rows
    float acc[4][8];
#pragma unroll
    for (int i = 0; i < 4; ++i)
#pragma unroll
        for (int jj = 0; jj < 8; ++jj) acc[i][jj] = 0.f;

    for (int st = 0; st < 2; ++st) {
        // stage A: 128 rows x 64 cols of this k-half
#pragma unroll
        for (int it = 0; it < 8; ++it) {
            int idx = tid + it * 256;            // 0..2047
            int r = idx >> 4, c4 = idx & 15;
            float4 a = *(const float4*)(Agg + (size_t)(rb * 128 + r) * 128 + st * 64 + c4 * 4);
            *(float4*)&As[r][c4 * 4] = a;
        }
        // stage W: 64 k x 64 cols
#pragma unroll
        for (int it = 0; it < 4; ++it) {
            int idx = tid + it * 256;            // 0..1023
            int kk = idx >> 4, c4 = idx & 15;
            float4 w = *(const float4*)(W + (size_t)(st * 64 + kk) * 128 + cbk * 64 + c4 * 4);
            *(float4*)&Ws[kk][c4 * 4] = w;
        }
        __syncthreads();

        int tr4 = tr * 4, tc8 = tc * 8;
#pragma unroll
        for (int kk = 0; kk < 64; kk += 4) {
            float a[4][4];
            *(float4*)&a[0][0] = *(const float4*)&As[tr4 + 0][kk];
            *(float4*)&a[1][0] = *(const float4*)&As[tr4 + 1][kk];
            *(float4*)&a[2][0] = *(const float4*)&As[tr4 + 2][kk];
            *(float4*)&a[3][0] = *(const float4*)&As[tr4 + 3][kk];
            float w[4][8];
#pragma unroll
            for (int q = 0; q < 4; ++q) {
                *(float4*)&w[q][0] = *(const float4*)&Ws[kk + q][tc8];
                *(float4*)&w[q][4] = *(const float4*)&Ws[kk + q][tc8 + 4];
            }
#pragma unroll
            for (int q = 0; q < 4; ++q)
#pragma unroll
                for (int i = 0; i < 4; ++i)
#pragma unroll
                    for (int jj = 0; jj < 8; ++jj)
                        acc[i][jj] = fmaf(a[i][q], w[q][jj], acc[i][jj]);
        }
        __syncthreads();
    }

    int r0 = rb * 128 + tr * 4;
    int c0 = cbk * 64 + tc * 8;
#pragma unroll
    for (int i = 0; i < 4; ++i) {
        int r = r0 + i;
        float invd = 1.0f / (float)deg[r];
        float cp1 = (float)(cnt[r] + 1);
        float o[8];
#pragma unroll
        for (int jj = 0; jj < 8; ++jj)
            o[jj] = tanhf((acc[i][jj] + bvec[c0 + jj] * cp1) * invd);
        *(float4*)(Hout + (size_t)r * 128 + c0)     = make_float4(o[0], o[1], o[2], o[3]);
        *(float4*)(Hout + (size_t)r * 128 + c0 + 4) = make_float4(o[4], o[5], o[6], o[7]);
    }
}

// ---------------- last (scalar) layer ----------------

__global__ __launch_bounds__(256) void k_last_lin(const float* __restrict__ H4,
                                                  const float* __restrict__ Wl,
                                                  const float* __restrict__ bl,
                                                  float* __restrict__ tmp) {
    int wv = threadIdx.x >> 6, lane = threadIdx.x & 63;
    int v = blockIdx.x * 4 + wv;
    float2 h = ((const float2*)H4)[(size_t)v * 64 + lane];
    float2 w = ((const float2*)Wl)[lane];
    float s = h.x * w.x + h.y * w.y;
#pragma unroll
    for (int off = 32; off > 0; off >>= 1) s += __shfl_xor(s, off);
    if (lane == 0) tmp[v] = s + bl[0];
}

__global__ __launch_bounds__(256) void k_last_agg(const float* __restrict__ tmp,
                                                  const int* __restrict__ adj,
                                                  const int* __restrict__ cnt,
                                                  const int* __restrict__ deg,
                                                  float* __restrict__ lastc) {
    int v = blockIdx.x * 256 + threadIdx.x;
    if (v >= N_TOTAL) return;
    float s = tmp[v];
    int c = cnt[v]; if (c > MAXD) c = MAXD;
    const int* av = adj + (size_t)v * MAXD;
    for (int i = 0; i < c; ++i) s += tmp[av[i]];
    lastc[v] = tanhf(s / (float)deg[v]);
}

// ---------------- sort pool: exact bitonic (val desc, idx asc) ----------------

__global__ __launch_bounds__(256) void k_sort(const float* __restrict__ lastc,
                                              int* __restrict__ topk) {
    __shared__ float v[512];
    __shared__ int ix[512];
    int g = blockIdx.x, tid = threadIdx.x;
    for (int i = tid; i < 512; i += 256) { v[i] = lastc[g * NPG + i]; ix[i] = i; }
    __syncthreads();
    for (int ksz = 2; ksz <= 512; ksz <<= 1) {
        for (int jj = ksz >> 1; jj > 0; jj >>= 1) {
            for (int i = tid; i < 512; i += 256) {
                int p = i ^ jj;
                if (p > i) {
                    float va = v[i], vb = v[p];
                    int ia = ix[i], ib = ix[p];
                    bool b_before_a = (vb > va) || (vb == va && ib < ia);
                    bool up = (i & ksz) == 0;
                    bool sw = up ? b_before_a : !b_before_a;
                    if (sw) { v[i] = vb; v[p] = va; ix[i] = ib; ix[p] = ia; }
                }
            }
            __syncthreads();
        }
    }
    for (int k = tid; k < KTOP; k += 256) topk[g * KTOP + k] = g * NPG + ix[k];
}

// ---------------- CNN head (one block per graph) ----------------

__global__ __launch_bounds__(256) void k_head(const int* __restrict__ topk,
                                              const float* __restrict__ h0,
                                              const float* __restrict__ h1,
                                              const float* __restrict__ h2,
                                              const float* __restrict__ h3,
                                              const float* __restrict__ lastc,
                                              const float* __restrict__ c1w, const float* __restrict__ c1b,
                                              const float* __restrict__ c2w, const float* __restrict__ c2b,
                                              const float* __restrict__ d1w, const float* __restrict__ d1b,
                                              const float* __restrict__ d2w, const float* __restrict__ d2b,
                                              float* __restrict__ out) {
    __shared__ float P[16][521];     // pooled chunk, pad 521 (gcd->odd stride, conflict-free)
    __shared__ float Y1[16][64];
    __shared__ float Y1P[16][32];
    __shared__ float Y2[32][28];
    __shared__ float H1s[32];
    __shared__ float red[256];
    int g = blockIdx.x, tid = threadIdx.x;

    // conv1 over 513-dim pooled rows, 4 chunks of 16 rows
    for (int cc = 0; cc < 4; ++cc) {
        for (int kk = 0; kk < 16; ++kk) {
            int node = topk[g * KTOP + cc * 16 + kk];
            for (int d = tid; d < LATENT; d += 256) {
                float val;
                if (d < 512) {
                    const float* Hl = (d < 128) ? h0 : (d < 256) ? h1 : (d < 384) ? h2 : h3;
                    val = Hl[(size_t)node * 128 + (d & 127)];
                } else val = lastc[node];
                P[kk][d] = val;
            }
        }
        __syncthreads();
        int o = tid >> 4, kk = tid & 15;
        float s = c1b[o];
        for (int d = 0; d < LATENT; ++d) s = fmaf(P[kk][d], c1w[o * LATENT + d], s);
        Y1[o][cc * 16 + kk] = fmaxf(s, 0.f);
        __syncthreads();
    }
    // maxpool(2,2): 16 channels x 32 outputs = 512 entries, strided over 256 threads
    for (int t = tid; t < 512; t += 256) {
        int o = t >> 5, l = t & 31;
        Y1P[o][l] = fmaxf(Y1[o][2 * l], Y1[o][2 * l + 1]);
    }
    __syncthreads();
    // conv2 (16->32, kernel 5, VALID -> 28)
    for (int t = tid; t < 32 * 28; t += 256) {
        int o2 = t / 28, tt = t - o2 * 28;
        float s = c2b[o2];
#pragma unroll
        for (int i = 0; i < 16; ++i)
#pragma unroll
            for (int dt = 0; dt < 5; ++dt)
                s = fmaf(Y1P[i][tt + dt], c2w[o2 * 80 + i * 5 + dt], s);
        Y2[o2][tt] = fmaxf(s, 0.f);
    }
    __syncthreads();
    // dense1: 896 -> 32, 8 threads per output
    {
        int jcol = tid >> 3, part = tid & 7;
        float s = 0.f;
        for (int rr = 0; rr < 4; ++rr) {
            int o2 = part * 4 + rr;
            int base = o2 * 28;
            for (int tt = 0; tt < 28; ++tt)
                s = fmaf(Y2[o2][tt], d1w[(size_t)(base + tt) * 32 + jcol], s);
        }
        red[tid] = s;
        __syncthreads();
        if (part == 0) {
            float t = 0.f;
#pragma unroll
            for (int p = 0; p < 8; ++p) t += red[tid + p];
            H1s[jcol] = fmaxf(t + d1b[jcol], 0.f);
        }
        __syncthreads();
    }
    // dense2 + softmax
    if (tid == 0) {
        float l0 = d2b[0], l1 = d2b[1];
        for (int jc = 0; jc < 32; ++jc) {
            l0 = fmaf(H1s[jc], d2w[jc * 2 + 0], l0);
            l1 = fmaf(H1s[jc], d2w[jc * 2 + 1], l1);
        }
        float m = fmaxf(l0, l1);
        float e0 = expf(l0 - m), e1 = expf(l1 - m);
        float inv = 1.f / (e0 + e1);
        out[g * 2 + 0] = e0 * inv;
        out[g * 2 + 1] = e1 * inv;
    }
}

// ---------------- launch ----------------

extern "C" void kernel_launch(void* const* d_in, const int* in_sizes, int n_in,
                              void* d_out, int out_size, void* d_ws, size_t ws_size,
                              hipStream_t stream) {
    const int*   x    = (const int*)d_in[0];
    const int*   ei   = (const int*)d_in[1];
    const float* emb  = (const float*)d_in[3];
    const float* Wc   = (const float*)d_in[4];
    const float* bc   = (const float*)d_in[5];
    const float* Wl   = (const float*)d_in[6];
    const float* bl   = (const float*)d_in[7];
    const float* c1w  = (const float*)d_in[8];
    const float* c1b  = (const float*)d_in[9];
    const float* c2w  = (const float*)d_in[10];
    const float* c2b  = (const float*)d_in[11];
    const float* d1w  = (const float*)d_in[12];
    const float* d1b  = (const float*)d_in[13];
    const float* d2w  = (const float*)d_in[14];
    const float* d2b  = (const float*)d_in[15];
    float* out = (float*)d_out;

    char* ws = (char*)d_ws;
    int*   deg  = (int*)ws;            ws += (size_t)N_TOTAL * 4;
    int*   cnt  = (int*)ws;            ws += (size_t)N_TOTAL * 4;
    int*   adj  = (int*)ws;            ws += (size_t)N_TOTAL * MAXD * 4;
    float* H0   = (float*)ws;          ws += (size_t)N_TOTAL * 128 * 4;
    float* Agg  = (float*)ws;          ws += (size_t)N_TOTAL * 128 * 4;
    float* Hid0 = (float*)ws;          ws += (size_t)N_TOTAL * 128 * 4;
    float* Hid1 = (float*)ws;          ws += (size_t)N_TOTAL * 128 * 4;
    float* Hid2 = (float*)ws;          ws += (size_t)N_TOTAL * 128 * 4;
    float* Hid3 = (float*)ws;          ws += (size_t)N_TOTAL * 128 * 4;
    float* tmp  = (float*)ws;          ws += (size_t)N_TOTAL * 4;
    float* lastc= (float*)ws;          ws += (size_t)N_TOTAL * 4;
    int*   topk = (int*)ws;            ws += (size_t)NUM_GRAPHS * KTOP * 4;

    k_init <<<N_TOTAL / 256, 256, 0, stream>>>(deg, cnt);
    k_build<<<E_TOTAL / 256, 256, 0, stream>>>(ei, deg, cnt, adj);
    k_embed<<<N_TOTAL * 32 / 256, 256, 0, stream>>>(x, emb, H0);

    float* Hids[4] = {Hid0, Hid1, Hid2, Hid3};
    const float* Hin = H0;
    for (int l = 0; l < 4; ++l) {
        k_agg<<<N_TOTAL / 4, 256, 0, stream>>>(Hin, Agg, adj, cnt);
        k_gemm_tanh<<<(N_TOTAL / 128) * 2, 256, 0, stream>>>(Agg, Wc + (size_t)l * 128 * 128,
                                                             bc + (size_t)l * 128, Hids[l], cnt, deg);
        Hin = Hids[l];
    }
    k_last_lin<<<N_TOTAL / 4, 256, 0, stream>>>(Hid3, Wl, bl, tmp);
    k_last_agg<<<N_TOTAL / 256, 256, 0, stream>>>(tmp, adj, cnt, deg, lastc);
    k_sort<<<NUM_GRAPHS, 256, 0, stream>>>(lastc, topk);
    k_head<<<NUM_GRAPHS, 256, 0, stream>>>(topk, Hid0, Hid1, Hid2, Hid3, lastc,
                                           c1w, c1b, c2w, c2b, d1w, d1b, d2w, d2b, out);
}

// Round 3
// 359.224 us; speedup vs baseline: 1.3101x; 1.3101x over previous
//
#include <hip/hip_runtime.h>
#include <hip/hip_bf16.h>
#include <math.h>

#define N_TOTAL 32768
#define E_TOTAL 524288
#define NUM_GRAPHS 64
#define NPG 512
#define EMB 128
#define MAXD 64
#define KTOP 64
#define LATENT 513
#define PPAD 524

// ---------------- setup kernels ----------------

__global__ __launch_bounds__(256) void k_init(int* __restrict__ deg, int* __restrict__ cnt) {
    int i = blockIdx.x * 256 + threadIdx.x;
    if (i < N_TOTAL) { deg[i] = 1; cnt[i] = 0; }   // deg starts at 1 (self loop in src concat)
}

__global__ __launch_bounds__(256) void k_build(const int* __restrict__ ei,
                                               int* __restrict__ deg, int* __restrict__ cnt,
                                               int* __restrict__ adj) {
    int e = blockIdx.x * 256 + threadIdx.x;
    if (e >= E_TOTAL) return;
    int s = ei[e];
    int d = ei[E_TOTAL + e];
    atomicAdd(&deg[s], 1);
    int slot = atomicAdd(&cnt[d], 1);
    if (slot < MAXD) adj[(size_t)d * MAXD + slot] = s;
}

// ---------------- aggregation: Agg[v] = H[v] + sum_{u in in(v)} H[u] ----------------
// Layer 0 reads rows from emb[x[u]] directly (k_embed fused away).

__global__ __launch_bounds__(256) void k_agg0(const int* __restrict__ x,
                                              const float* __restrict__ emb,
                                              float* __restrict__ Agg,
                                              const int* __restrict__ adj,
                                              const int* __restrict__ cnt) {
    int bid = blockIdx.x;                 // 8192 blocks
    int xcd = bid & 7;
    int j = bid >> 3;
    int g = (xcd << 3) + (j >> 7);        // 8 graphs per XCD -> per-XCD L2 residency
    int chunk = j & 127;
    int wv = threadIdx.x >> 6, lane = threadIdx.x & 63;
    int v = g * NPG + chunk * 4 + wv;

    int c = cnt[v]; if (c > MAXD) c = MAXD;
    const int* av = adj + (size_t)v * MAXD;
    int nb = (lane < c) ? av[lane] : v;   // neighbor index per lane (broadcast later)
    int xnb = x[nb];                      // node-id -> vocab id, prefetched per lane
    const float2* e2 = (const float2*)emb;
    float2 s = e2[(size_t)x[v] * 64 + lane];          // self loop
    for (int i = 0; i < c; ++i) {
        int u = __shfl(xnb, i);
        float2 t = e2[(size_t)u * 64 + lane];
        s.x += t.x; s.y += t.y;
    }
    ((float2*)Agg)[(size_t)v * 64 + lane] = s;
}

__global__ __launch_bounds__(256) void k_agg(const float* __restrict__ Hin,
                                             float* __restrict__ Agg,
                                             const int* __restrict__ adj,
                                             const int* __restrict__ cnt) {
    int bid = blockIdx.x;                 // 8192 blocks
    int xcd = bid & 7;
    int j = bid >> 3;
    int g = (xcd << 3) + (j >> 7);
    int chunk = j & 127;
    int wv = threadIdx.x >> 6, lane = threadIdx.x & 63;
    int v = g * NPG + chunk * 4 + wv;

    int c = cnt[v]; if (c > MAXD) c = MAXD;
    const int* av = adj + (size_t)v * MAXD;
    int nb = (lane < c) ? av[lane] : 0;   // all ≤64 neighbor ids live in lanes
    const float2* hin = (const float2*)Hin;
    float2 s = hin[(size_t)v * 64 + lane];          // self loop
    for (int i = 0; i < c; ++i) {
        int u = __shfl(nb, i);            // no memory dependency -> gathers pipeline
        float2 t = hin[(size_t)u * 64 + lane];
        s.x += t.x; s.y += t.y;
    }
    ((float2*)Agg)[(size_t)v * 64 + lane] = s;
}

// ---------------- GEMM + bias + 1/deg + tanh:  Hout = tanh((Agg@W + (cnt+1)b)/deg) ---------

__global__ __launch_bounds__(256) void k_gemm_tanh(const float* __restrict__ Agg,
                                                   const float* __restrict__ W,
                                                   const float* __restrict__ bvec,
                                                   float* __restrict__ Hout,
                                                   const int* __restrict__ cnt,
                                                   const int* __restrict__ deg) {
    __shared__ float As[128][68];   // 128 rows x 64 k-half, pad to 68 (16B-aligned rows)
    __shared__ float Ws[64][64];    // 64 k x 64 cols
    int tid = threadIdx.x;
    int bid = blockIdx.x;
    int rb = bid >> 1, cbk = bid & 1;
    int tc = tid & 7;               // 8 col groups of 8 cols
    int tr = tid >> 3;              // 32 row groups of 4 rows
    float acc[4][8];
#pragma unroll
    for (int i = 0; i < 4; ++i)
#pragma unroll
        for (int jj = 0; jj < 8; ++jj) acc[i][jj] = 0.f;

    for (int st = 0; st < 2; ++st) {
#pragma unroll
        for (int it = 0; it < 8; ++it) {
            int idx = tid + it * 256;            // 0..2047
            int r = idx >> 4, c4 = idx & 15;
            float4 a = *(const float4*)(Agg + (size_t)(rb * 128 + r) * 128 + st * 64 + c4 * 4);
            *(float4*)&As[r][c4 * 4] = a;
        }
#pragma unroll
        for (int it = 0; it < 4; ++it) {
            int idx = tid + it * 256;            // 0..1023
            int kk = idx >> 4, c4 = idx & 15;
            float4 w = *(const float4*)(W + (size_t)(st * 64 + kk) * 128 + cbk * 64 + c4 * 4);
            *(float4*)&Ws[kk][c4 * 4] = w;
        }
        __syncthreads();

        int tr4 = tr * 4, tc8 = tc * 8;
#pragma unroll
        for (int kk = 0; kk < 64; kk += 4) {
            float a[4][4];
            *(float4*)&a[0][0] = *(const float4*)&As[tr4 + 0][kk];
            *(float4*)&a[1][0] = *(const float4*)&As[tr4 + 1][kk];
            *(float4*)&a[2][0] = *(const float4*)&As[tr4 + 2][kk];
            *(float4*)&a[3][0] = *(const float4*)&As[tr4 + 3][kk];
            float w[4][8];
#pragma unroll
            for (int q = 0; q < 4; ++q) {
                *(float4*)&w[q][0] = *(const float4*)&Ws[kk + q][tc8];
                *(float4*)&w[q][4] = *(const float4*)&Ws[kk + q][tc8 + 4];
            }
#pragma unroll
            for (int q = 0; q < 4; ++q)
#pragma unroll
                for (int i = 0; i < 4; ++i)
#pragma unroll
                    for (int jj = 0; jj < 8; ++jj)
                        acc[i][jj] = fmaf(a[i][q], w[q][jj], acc[i][jj]);
        }
        __syncthreads();
    }

    int r0 = rb * 128 + tr * 4;
    int c0 = cbk * 64 + tc * 8;
#pragma unroll
    for (int i = 0; i < 4; ++i) {
        int r = r0 + i;
        float invd = 1.0f / (float)deg[r];
        float cp1 = (float)(cnt[r] + 1);
        float o[8];
#pragma unroll
        for (int jj = 0; jj < 8; ++jj)
            o[jj] = tanhf((acc[i][jj] + bvec[c0 + jj] * cp1) * invd);
        *(float4*)(Hout + (size_t)r * 128 + c0)     = make_float4(o[0], o[1], o[2], o[3]);
        *(float4*)(Hout + (size_t)r * 128 + c0 + 4) = make_float4(o[4], o[5], o[6], o[7]);
    }
}

// ---------------- last (scalar) layer ----------------

__global__ __launch_bounds__(256) void k_last_lin(const float* __restrict__ H4,
                                                  const float* __restrict__ Wl,
                                                  const float* __restrict__ bl,
                                                  float* __restrict__ tmp) {
    int wv = threadIdx.x >> 6, lane = threadIdx.x & 63;
    int v = blockIdx.x * 4 + wv;
    float2 h = ((const float2*)H4)[(size_t)v * 64 + lane];
    float2 w = ((const float2*)Wl)[lane];
    float s = h.x * w.x + h.y * w.y;
#pragma unroll
    for (int off = 32; off > 0; off >>= 1) s += __shfl_xor(s, off);
    if (lane == 0) tmp[v] = s + bl[0];
}

__global__ __launch_bounds__(256) void k_last_agg(const float* __restrict__ tmp,
                                                  const int* __restrict__ adj,
                                                  const int* __restrict__ cnt,
                                                  const int* __restrict__ deg,
                                                  float* __restrict__ lastc) {
    int v = blockIdx.x * 256 + threadIdx.x;
    if (v >= N_TOTAL) return;
    float s = tmp[v];
    int c = cnt[v]; if (c > MAXD) c = MAXD;
    const int* av = adj + (size_t)v * MAXD;
    for (int i = 0; i < c; ++i) s += tmp[av[i]];
    lastc[v] = tanhf(s / (float)deg[v]);
}

// ---------------- sort pool: exact bitonic (val desc, idx asc) ----------------

__global__ __launch_bounds__(256) void k_sort(const float* __restrict__ lastc,
                                              int* __restrict__ topk) {
    __shared__ float v[512];
    __shared__ int ix[512];
    int g = blockIdx.x, tid = threadIdx.x;
    for (int i = tid; i < 512; i += 256) { v[i] = lastc[g * NPG + i]; ix[i] = i; }
    __syncthreads();
    for (int ksz = 2; ksz <= 512; ksz <<= 1) {
        for (int jj = ksz >> 1; jj > 0; jj >>= 1) {
            for (int i = tid; i < 512; i += 256) {
                int p = i ^ jj;
                if (p > i) {
                    float va = v[i], vb = v[p];
                    int ia = ix[i], ib = ix[p];
                    bool b_before_a = (vb > va) || (vb == va && ib < ia);
                    bool up = (i & ksz) == 0;
                    bool sw = up ? b_before_a : !b_before_a;
                    if (sw) { v[i] = vb; v[p] = va; ix[i] = ib; ix[p] = ia; }
                }
            }
            __syncthreads();
        }
    }
    for (int k = tid; k < KTOP; k += 256) topk[g * KTOP + k] = g * NPG + ix[k];
}

// ---------------- conv1 + relu + maxpool: 256 blocks (64 graphs x 4 chunks of 16 rows) ----

__global__ __launch_bounds__(256) void k_conv1(const int* __restrict__ topk,
                                               const float* __restrict__ h0,
                                               const float* __restrict__ h1,
                                               const float* __restrict__ h2,
                                               const float* __restrict__ h3,
                                               const float* __restrict__ lastc,
                                               const float* __restrict__ c1w,
                                               const float* __restrict__ c1b,
                                               float* __restrict__ y1p) {
    __shared__ float P[16][PPAD];     // 16 pooled rows x 513 (pad 524 -> rows 16B-aligned)
    __shared__ float Y1c[16][16];     // [o][kk_local]
    __shared__ int nodes[16];
    int bid = blockIdx.x;
    int g = bid >> 2, cc = bid & 3;
    int tid = threadIdx.x;
    if (tid < 16) nodes[tid] = topk[g * KTOP + cc * 16 + tid];
    __syncthreads();

    // stage: 16 threads per row, float4 loads (all rows in parallel, fully pipelined)
    {
        int r = tid >> 4, t4 = tid & 15;
        int node = nodes[r];
#pragma unroll
        for (int jj = 0; jj < 8; ++jj) {
            int d = (t4 + 16 * jj) * 4;                 // 0..508, step 4
            const float* src = (d < 128) ? h0 : (d < 256) ? h1 : (d < 384) ? h2 : h3;
            float4 val = *(const float4*)(src + (size_t)node * 128 + (d & 127));
            *(float4*)&P[r][d] = val;
        }
        if (t4 == 0) P[r][512] = lastc[node];
    }
    __syncthreads();

    // conv1: thread (o, kk); 4 independent accumulator chains
    int o = tid >> 4, kk = tid & 15;
    const float* w = c1w + (size_t)o * LATENT;
    float a0 = 0.f, a1 = 0.f, a2 = 0.f, a3 = 0.f;
    for (int d = 0; d < 512; d += 4) {
        float4 p = *(const float4*)&P[kk][d];
        a0 = fmaf(p.x, w[d],     a0);
        a1 = fmaf(p.y, w[d + 1], a1);
        a2 = fmaf(p.z, w[d + 2], a2);
        a3 = fmaf(p.w, w[d + 3], a3);
    }
    float s = ((a0 + a1) + (a2 + a3)) + P[kk][512] * w[512] + c1b[o];
    Y1c[o][kk] = fmaxf(s, 0.f);
    __syncthreads();

    // relu done; maxpool(2,2) within the 16-row chunk -> 8 pooled positions
    if (tid < 128) {
        int oo = tid >> 3, l = tid & 7;
        y1p[(size_t)g * 512 + oo * 32 + cc * 8 + l] = fmaxf(Y1c[oo][2 * l], Y1c[oo][2 * l + 1]);
    }
}

// ---------------- conv2 + dense + softmax: 64 blocks ----------------

__global__ __launch_bounds__(256) void k_tail(const float* __restrict__ y1p,
                                              const float* __restrict__ c2w, const float* __restrict__ c2b,
                                              const float* __restrict__ d1w, const float* __restrict__ d1b,
                                              const float* __restrict__ d2w, const float* __restrict__ d2b,
                                              float* __restrict__ out) {
    __shared__ float Y1P[16][32];
    __shared__ float Y2[32][28];
    __shared__ float H1s[32];
    __shared__ float red[256];
    int g = blockIdx.x, tid = threadIdx.x;

    for (int t = tid; t < 512; t += 256) ((float*)Y1P)[t] = y1p[(size_t)g * 512 + t];
    __syncthreads();

    // conv2 (16->32, kernel 5, VALID -> 28)
    for (int t = tid; t < 32 * 28; t += 256) {
        int o2 = t / 28, tt = t - o2 * 28;
        float s = c2b[o2];
#pragma unroll
        for (int i = 0; i < 16; ++i)
#pragma unroll
            for (int dt = 0; dt < 5; ++dt)
                s = fmaf(Y1P[i][tt + dt], c2w[o2 * 80 + i * 5 + dt], s);
        Y2[o2][tt] = fmaxf(s, 0.f);
    }
    __syncthreads();

    // dense1: 896 -> 32, 8 threads per output
    {
        int jcol = tid >> 3, part = tid & 7;
        float s = 0.f;
        for (int rr = 0; rr < 4; ++rr) {
            int o2 = part * 4 + rr;
            int base = o2 * 28;
            for (int tt = 0; tt < 28; ++tt)
                s = fmaf(Y2[o2][tt], d1w[(size_t)(base + tt) * 32 + jcol], s);
        }
        red[tid] = s;
        __syncthreads();
        if (part == 0) {
            float t = 0.f;
#pragma unroll
            for (int p = 0; p < 8; ++p) t += red[tid + p];
            H1s[jcol] = fmaxf(t + d1b[jcol], 0.f);
        }
        __syncthreads();
    }

    // dense2 + softmax
    if (tid == 0) {
        float l0 = d2b[0], l1 = d2b[1];
        for (int jc = 0; jc < 32; ++jc) {
            l0 = fmaf(H1s[jc], d2w[jc * 2 + 0], l0);
            l1 = fmaf(H1s[jc], d2w[jc * 2 + 1], l1);
        }
        float m = fmaxf(l0, l1);
        float e0 = expf(l0 - m), e1 = expf(l1 - m);
        float inv = 1.f / (e0 + e1);
        out[g * 2 + 0] = e0 * inv;
        out[g * 2 + 1] = e1 * inv;
    }
}

// ---------------- launch ----------------

extern "C" void kernel_launch(void* const* d_in, const int* in_sizes, int n_in,
                              void* d_out, int out_size, void* d_ws, size_t ws_size,
                              hipStream_t stream) {
    const int*   x    = (const int*)d_in[0];
    const int*   ei   = (const int*)d_in[1];
    const float* emb  = (const float*)d_in[3];
    const float* Wc   = (const float*)d_in[4];
    const float* bc   = (const float*)d_in[5];
    const float* Wl   = (const float*)d_in[6];
    const float* bl   = (const float*)d_in[7];
    const float* c1w  = (const float*)d_in[8];
    const float* c1b  = (const float*)d_in[9];
    const float* c2w  = (const float*)d_in[10];
    const float* c2b  = (const float*)d_in[11];
    const float* d1w  = (const float*)d_in[12];
    const float* d1b  = (const float*)d_in[13];
    const float* d2w  = (const float*)d_in[14];
    const float* d2b  = (const float*)d_in[15];
    float* out = (float*)d_out;

    char* ws = (char*)d_ws;
    int*   deg  = (int*)ws;            ws += (size_t)N_TOTAL * 4;
    int*   cnt  = (int*)ws;            ws += (size_t)N_TOTAL * 4;
    int*   adj  = (int*)ws;            ws += (size_t)N_TOTAL * MAXD * 4;
    float* Agg  = (float*)ws;          ws += (size_t)N_TOTAL * 128 * 4;
    float* Hid0 = (float*)ws;          ws += (size_t)N_TOTAL * 128 * 4;
    float* Hid1 = (float*)ws;          ws += (size_t)N_TOTAL * 128 * 4;
    float* Hid2 = (float*)ws;          ws += (size_t)N_TOTAL * 128 * 4;
    float* Hid3 = (float*)ws;          ws += (size_t)N_TOTAL * 128 * 4;
    float* tmp  = (float*)ws;          ws += (size_t)N_TOTAL * 4;
    float* lastc= (float*)ws;          ws += (size_t)N_TOTAL * 4;
    int*   topk = (int*)ws;            ws += (size_t)NUM_GRAPHS * KTOP * 4;
    float* y1p  = (float*)ws;          ws += (size_t)NUM_GRAPHS * 16 * 32 * 4;

    k_init <<<N_TOTAL / 256, 256, 0, stream>>>(deg, cnt);
    k_build<<<E_TOTAL / 256, 256, 0, stream>>>(ei, deg, cnt, adj);

    float* Hids[4] = {Hid0, Hid1, Hid2, Hid3};
    for (int l = 0; l < 4; ++l) {
        if (l == 0)
            k_agg0<<<N_TOTAL / 4, 256, 0, stream>>>(x, emb, Agg, adj, cnt);
        else
            k_agg<<<N_TOTAL / 4, 256, 0, stream>>>(Hids[l - 1], Agg, adj, cnt);
        k_gemm_tanh<<<(N_TOTAL / 128) * 2, 256, 0, stream>>>(Agg, Wc + (size_t)l * 128 * 128,
                                                             bc + (size_t)l * 128, Hids[l], cnt, deg);
    }
    k_last_lin<<<N_TOTAL / 4, 256, 0, stream>>>(Hid3, Wl, bl, tmp);
    k_last_agg<<<N_TOTAL / 256, 256, 0, stream>>>(tmp, adj, cnt, deg, lastc);
    k_sort<<<NUM_GRAPHS, 256, 0, stream>>>(lastc, topk);
    k_conv1<<<NUM_GRAPHS * 4, 256, 0, stream>>>(topk, Hid0, Hid1, Hid2, Hid3, lastc, c1w, c1b, y1p);
    k_tail<<<NUM_GRAPHS, 256, 0, stream>>>(y1p, c2w, c2b, d1w, d1b, d2w, d2b, out);
}